// Round 2
// baseline (238.409 us; speedup 1.0000x reference)
//
#include <hip/hip_runtime.h>
#include <hip/hip_bf16.h>
#include <cstdint>

#define N_ATOMS 100000
#define NFEAT   256
#define NMOL    1024
#define NU      6256    // 100096 / 16 atoms per unit

static constexpr float SCALE_C = 5.992277830325989f;
static constexpr float SHIFT_C = -406274.63784969115f;

typedef __attribute__((ext_vector_type(8))) short short8;    // bf16x8 MFMA operand
typedef __attribute__((ext_vector_type(4))) float float4_t;  // f32x4 accumulator

__device__ __forceinline__ unsigned short f2bf(float x) {
    union { float f; uint32_t u; } v; v.f = x;
    uint32_t r = (v.u + 0x7fffu + ((v.u >> 16) & 1u)) >> 16;
    return (unsigned short)r;
}

// pack two fp32 -> two bf16 (round-half-up) in one v_perm
__device__ __forceinline__ uint32_t pk(float lo, float hi) {
    union { float f; uint32_t u; } a, b; a.f = lo; b.f = hi;
    return __builtin_amdgcn_perm(b.u + 0x8000u, a.u + 0x8000u, 0x07060302u);
}

__device__ __forceinline__ float silu(float x) {
    return x / (1.0f + __expf(-x));
}

// async global->LDS, 16B/lane; LDS dest wave-uniform, lane i lands at +i*16B
__device__ __forceinline__ void async16(void* lds, const void* g) {
    __builtin_amdgcn_global_load_lds(
        (const __attribute__((address_space(1))) unsigned int*)(uintptr_t)g,
        (__attribute__((address_space(3))) unsigned int*)(uint32_t)(uintptr_t)lds,
        16, 0, 0);
}

// Full 256x256 W image in LDS (R4-verified layout, 0 bank conflicts):
//   pos = (kc>>4)*32768 + n*128 + (((kc&15) ^ (n&15))<<3)  [+ (k&7)]
__device__ __forceinline__ short8 wfrag(const unsigned short* Wlds, int n, int kc) {
    return *(const short8*)&Wlds[((kc >> 4) << 15) + n * 128 +
                                 ((((kc & 15) ^ (n & 15)) & 15) << 3)];
}

// ---------------------------------------------------------------------------
// Prep: W1,W2 fp32 [k][n] -> bf16 swizzled plane images; init out[] = SHIFT.
// ---------------------------------------------------------------------------
__global__ void prep(const float* __restrict__ W1, const float* __restrict__ W2,
                     unsigned short* __restrict__ W1i, unsigned short* __restrict__ W2i,
                     float* __restrict__ out) {
    int g = blockIdx.x * 256 + threadIdx.x;          // 0 .. 131071
    const float* W = (g < 65536) ? W1 : W2;
    unsigned short* Wi = (g < 65536) ? W1i : W2i;
    int idx = g & 65535;
    int k = idx >> 8, n = idx & 255;
    int kc = (k >> 3) & 15;
    int pos = ((k >> 7) << 15) + n * 128 + (((kc ^ (n & 15)) & 15) << 3) + (k & 7);
    Wi[pos] = f2bf(W[idx]);
    if (g < NMOL) out[g] = SHIFT_C;
}

// ---------------------------------------------------------------------------
// Layer 1: H1 = silu(A @ W1 + b1). 1024 thr = 16 waves (4/SIMD), 1 block/CU;
// full W1 (128 KB) staged to LDS once, ONE barrier total.
// R8 lesson: 512thr/8waves was latency-bound (all pipes <25%).
// R9 lesson: __launch_bounds__(1024,4) clamped VGPR to 64 -> ~54 MB of
// scratch spill traffic (WRITE 50->84 MB), dur 62->90us. Use (1024,1):
// 1 block/CU, VGPR cap 128, natural ~88-reg allocation, no spill,
// 16 waves resident. Waves stream 16-atom x 256-col units via per-block
// LDS steal counter; A loads prefetched one k-step ahead (depth-2 pipeline).
// ---------------------------------------------------------------------------
__global__ __launch_bounds__(1024, 1)
void gemm1(const float* __restrict__ A, const unsigned short* __restrict__ Wimg,
           const float* __restrict__ b1, unsigned short* __restrict__ H1) {
    __shared__ unsigned short Wlds[65536];   // 128 KB
    __shared__ float b1L[256];
    __shared__ int uctr;

    const int tid = threadIdx.x;
    const int w = tid >> 6, lane = tid & 63;
    const int fl = lane & 15, qd = lane >> 4;

#pragma unroll
    for (int i = 0; i < 8; ++i)
        async16(&Wlds[(w * 8 + i) * 512], Wimg + (w * 8 + i) * 512 + lane * 8);
    if (tid < 64) ((float4*)b1L)[tid] = ((const float4*)b1)[tid];
    if (tid == 0) uctr = 0;
    __syncthreads();

    for (;;) {
        int t = 0;
        if (lane == 0) t = atomicAdd(&uctr, 1);   // LDS atomic
        t = __shfl(t, 0);
        const int u = blockIdx.x + (t << 8);      // stride-256 across blocks
        if (u >= NU) break;

        const int row = u * 16 + fl;              // this lane's atom
        const bool valid = row < N_ATOMS;
        const float* ap = A + (size_t)row * 256 + qd * 8;

        float4 c0, c1;
        if (valid) { c0 = *(const float4*)ap; c1 = *(const float4*)(ap + 4); }
        else       { c0 = make_float4(0, 0, 0, 0); c1 = c0; }

        float4_t acc[16] = {};
#pragma unroll
        for (int s = 0; s < 8; ++s) {
            float4 n0 = make_float4(0, 0, 0, 0), n1 = n0;
            if (s < 7 && valid) {                  // prefetch next k-step
                n0 = *(const float4*)(ap + (s + 1) * 32);
                n1 = *(const float4*)(ap + (s + 1) * 32 + 4);
            }
            union { uint32_t u4[4]; short8 s8; } cv;
            cv.u4[0] = pk(c0.x, c0.y); cv.u4[1] = pk(c0.z, c0.w);
            cv.u4[2] = pk(c1.x, c1.y); cv.u4[3] = pk(c1.z, c1.w);
            const int kc = s * 4 + qd;
#pragma unroll
            for (int j = 0; j < 16; ++j) {
                short8 wf = wfrag(Wlds, j * 16 + fl, kc);
                acc[j] = __builtin_amdgcn_mfma_f32_16x16x32_bf16(wf, cv.s8, acc[j], 0, 0, 0);
            }
            c0 = n0; c1 = n1;
        }

        if (valid) {
#pragma unroll
            for (int j = 0; j < 16; ++j) {
                int nb = j * 16 + qd * 4;
                float4 b4 = *(const float4*)&b1L[nb];
                uint2 o;
                o.x = pk(silu(acc[j][0] + b4.x), silu(acc[j][1] + b4.y));
                o.y = pk(silu(acc[j][2] + b4.z), silu(acc[j][3] + b4.w));
                *(uint2*)&H1[(size_t)row * 256 + nb] = o;
            }
        }
    }
}

// ---------------------------------------------------------------------------
// Layer 2+3+pool: out[mol] += SCALE*(silu(H1@W2+b2).W3 + b3). Same streaming
// structure (16 waves, launch_bounds(1024,1) per R9 spill lesson), natural
// operand order; unit covers ALL 256 cols so b3 is added once per atom.
// Pooling via LDS bucket[1024] (R7-verified), one global atomic per nonzero
// bucket at the end.
// ---------------------------------------------------------------------------
__global__ __launch_bounds__(1024, 1)
void gemm2(const unsigned short* __restrict__ H1, const unsigned short* __restrict__ Wimg,
           const float* __restrict__ b2, const float* __restrict__ W3,
           const float* __restrict__ b3, const int* __restrict__ batch,
           float* __restrict__ out) {
    __shared__ unsigned short Wlds[65536];   // 128 KB
    __shared__ float bucket[NMOL];           // 4 KB
    __shared__ int uctr;

    const int tid = threadIdx.x;
    const int w = tid >> 6, lane = tid & 63;
    const int fl = lane & 15, qd = lane >> 4;

#pragma unroll
    for (int i = 0; i < 8; ++i)
        async16(&Wlds[(w * 8 + i) * 512], Wimg + (w * 8 + i) * 512 + lane * 8);
    bucket[tid] = 0.0f;
    if (tid == 0) uctr = 0;
    __syncthreads();

    const float b3v = b3[0];
    float bbv[16], w3v[16];
#pragma unroll
    for (int nt = 0; nt < 16; ++nt) {
        bbv[nt] = b2[nt * 16 + fl];
        w3v[nt] = W3[nt * 16 + fl];
    }

    for (;;) {
        int t = 0;
        if (lane == 0) t = atomicAdd(&uctr, 1);
        t = __shfl(t, 0);
        const int u = blockIdx.x + (t << 8);
        if (u >= NU) break;

        const int ubase = u * 16;
        const int row = ubase + fl;
        const bool valid = row < N_ATOMS;
        const unsigned short* hp = H1 + (size_t)row * 256 + qd * 8;

        short8 h0 = (short8){0, 0, 0, 0, 0, 0, 0, 0};
        if (valid) h0 = *(const short8*)hp;

        float4_t acc[16] = {};
#pragma unroll
        for (int s = 0; s < 8; ++s) {
            short8 hn = (short8){0, 0, 0, 0, 0, 0, 0, 0};
            if (s < 7 && valid) hn = *(const short8*)(hp + (s + 1) * 32);
            const int kc = s * 4 + qd;
#pragma unroll
            for (int nt = 0; nt < 16; ++nt) {
                short8 wf = wfrag(Wlds, nt * 16 + fl, kc);
                acc[nt] = __builtin_amdgcn_mfma_f32_16x16x32_bf16(h0, wf, acc[nt], 0, 0, 0);
            }
            h0 = hn;
        }

        // acc[nt][r]: atom = ubase + qd*4 + r, col = nt*16 + fl
        float rs[4] = {};
#pragma unroll
        for (int nt = 0; nt < 16; ++nt)
#pragma unroll
            for (int r = 0; r < 4; ++r)
                rs[r] += silu(acc[nt][r] + bbv[nt]) * w3v[nt];
#pragma unroll
        for (int r = 0; r < 4; ++r) {
            float v = rs[r];
            v += __shfl_xor(v, 1);
            v += __shfl_xor(v, 2);
            v += __shfl_xor(v, 4);
            v += __shfl_xor(v, 8);
            rs[r] = v;
        }
        if (fl == 0) {
            int atom0 = ubase + qd * 4;
            if (atom0 < N_ATOMS) {   // atom0 % 4 == 0 -> all 4 rows valid
                int4 mb = *(const int4*)&batch[atom0];
                float v0 = rs[0] + b3v, v1 = rs[1] + b3v,
                      v2 = rs[2] + b3v, v3 = rs[3] + b3v;
                if (mb.x == mb.w) {
                    atomicAdd(&bucket[mb.x], (v0 + v1) + (v2 + v3));
                } else {
                    atomicAdd(&bucket[mb.x], v0);
                    atomicAdd(&bucket[mb.y], v1);
                    atomicAdd(&bucket[mb.z], v2);
                    atomicAdd(&bucket[mb.w], v3);
                }
            }
        }
    }
    __syncthreads();
    {
        float v = bucket[tid];
        if (v != 0.0f) atomicAdd(&out[tid], v * SCALE_C);
    }
}

// ---------------------------------------------------------------------------
extern "C" void kernel_launch(void* const* d_in, const int* in_sizes, int n_in,
                              void* d_out, int out_size, void* d_ws, size_t ws_size,
                              hipStream_t stream) {
    const float* A     = (const float*)d_in[0];
    const int*   batch = (const int*)d_in[1];
    const float* W1    = (const float*)d_in[2];
    const float* b1    = (const float*)d_in[3];
    const float* W2    = (const float*)d_in[4];
    const float* b2    = (const float*)d_in[5];
    const float* W3    = (const float*)d_in[6];
    const float* b3    = (const float*)d_in[7];
    float* out = (float*)d_out;

    unsigned short* H1  = (unsigned short*)d_ws;            // 100096*256 bf16
    unsigned short* W1i = H1 + (size_t)100096 * NFEAT;      // 65536 shorts
    unsigned short* W2i = W1i + 65536;                      // 65536 shorts

    prep<<<dim3(512), 256, 0, stream>>>(W1, W2, W1i, W2i, out);
    gemm1<<<dim3(256), 1024, 0, stream>>>(A, W1i, b1, H1);
    gemm2<<<dim3(256), 1024, 0, stream>>>(H1, W2i, b2, W3, b3, batch, out);
}

// Round 3
// 210.800 us; speedup vs baseline: 1.1310x; 1.1310x over previous
//
#include <hip/hip_runtime.h>
#include <hip/hip_bf16.h>
#include <cstdint>

#define N_ATOMS 100000
#define NFEAT   256
#define NMOL    1024
#define NU      6256    // 100096 / 16 atoms per unit

static constexpr float SCALE_C = 5.992277830325989f;
static constexpr float SHIFT_C = -406274.63784969115f;

typedef __attribute__((ext_vector_type(8))) short short8;    // bf16x8 MFMA operand
typedef __attribute__((ext_vector_type(4))) float float4_t;  // f32x4 accumulator

__device__ __forceinline__ unsigned short f2bf(float x) {
    union { float f; uint32_t u; } v; v.f = x;
    uint32_t r = (v.u + 0x7fffu + ((v.u >> 16) & 1u)) >> 16;
    return (unsigned short)r;
}

// pack two fp32 -> two bf16 (round-half-up) in one v_perm
__device__ __forceinline__ uint32_t pk(float lo, float hi) {
    union { float f; uint32_t u; } a, b; a.f = lo; b.f = hi;
    return __builtin_amdgcn_perm(b.u + 0x8000u, a.u + 0x8000u, 0x07060302u);
}

__device__ __forceinline__ float silu(float x) {
    return x / (1.0f + __expf(-x));
}

// async global->LDS, 16B/lane; LDS dest wave-uniform, lane i lands at +i*16B
__device__ __forceinline__ void async16(void* lds, const void* g) {
    __builtin_amdgcn_global_load_lds(
        (const __attribute__((address_space(1))) unsigned int*)(uintptr_t)g,
        (__attribute__((address_space(3))) unsigned int*)(uint32_t)(uintptr_t)lds,
        16, 0, 0);
}

// Global W image (written by prep, unchanged R4-verified layout):
//   pos = (k>>7)*32768 + n*128 + (((k>>3 & 15) ^ (n&15))&15)<<3 + (k&7)
// Column-half extraction (R10): cols [ch*128, ch*128+128) of plane p are the
// CONTIGUOUS 32 KB at offset p*32768 + ch*16384 (n*128 makes cols contiguous).
//
// LDS holds one 64 KB col-half: lpos = (kc>>4)*16384 + n'*128 + swz, n'=n-ch*128.
// Swizzle uses n&15 == n'&15 (ch*128 % 16 == 0), so layout math is unchanged.
__device__ __forceinline__ short8 wfrag_h(const unsigned short* Wlds, int nl, int kc) {
    return *(const short8*)&Wlds[((kc >> 4) << 14) + nl * 128 +
                                 ((((kc & 15) ^ (nl & 15)) & 15) << 3)];
}

// ---------------------------------------------------------------------------
// Prep: W1,W2 fp32 [k][n] -> bf16 swizzled plane images; init out[] = SHIFT.
// ---------------------------------------------------------------------------
__global__ void prep(const float* __restrict__ W1, const float* __restrict__ W2,
                     unsigned short* __restrict__ W1i, unsigned short* __restrict__ W2i,
                     float* __restrict__ out) {
    int g = blockIdx.x * 256 + threadIdx.x;          // 0 .. 131071
    const float* W = (g < 65536) ? W1 : W2;
    unsigned short* Wi = (g < 65536) ? W1i : W2i;
    int idx = g & 65535;
    int k = idx >> 8, n = idx & 255;
    int kc = (k >> 3) & 15;
    int pos = ((k >> 7) << 15) + n * 128 + (((kc ^ (n & 15)) & 15) << 3) + (k & 7);
    Wi[pos] = f2bf(W[idx]);
    if (g < NMOL) out[g] = SHIFT_C;
}

// ---------------------------------------------------------------------------
// Layer 1: H1 = silu(A @ W1 + b1).
// R9/R10 lesson: 1024-thr blocks force 4 waves/EU co-residency -> 128-reg
// unified cap; acc[16]=64 leaves 64 arch -> ~54 MB spill traffic. Fix:
// COLUMN-SPLIT. 512 blocks x 512 thr; block (bslot, ch) owns col-half
// ch*128..+127 (64 KB LDS W image) -> 2 blocks/CU, 16 waves/CU, acc[8]=32,
// ~90 total regs < 128 cap of __launch_bounds__(512,4). No spill + double
// occupancy vs R0. Cost: A row read by both halves; pair (b, b+256) is on
// the SAME XCD (256%8==0) so 2nd read hits that XCD's L2.
// Waves stream 16-atom x 128-col units via per-block LDS steal counter;
// A loads prefetched one k-step ahead (depth-2 pipeline).
// ---------------------------------------------------------------------------
__global__ __launch_bounds__(512, 4)
void gemm1(const float* __restrict__ A, const unsigned short* __restrict__ Wimg,
           const float* __restrict__ b1, unsigned short* __restrict__ H1) {
    __shared__ unsigned short Wlds[32768];   // 64 KB: one col-half, both k-planes
    __shared__ float b1L[128];
    __shared__ int uctr;

    const int tid = threadIdx.x;
    const int w = tid >> 6, lane = tid & 63;
    const int fl = lane & 15, qd = lane >> 4;
    const int ch = blockIdx.x >> 8;          // col-half 0/1
    const int bslot = blockIdx.x & 255;

    // stage 64 KB half: chunk c (512 shorts) -> plane p=c>>5, in-plane (c&31)*512
#pragma unroll
    for (int i = 0; i < 8; ++i) {
        int c = w * 8 + i;
        async16(&Wlds[c * 512],
                Wimg + ((c >> 5) << 15) + (ch << 14) + ((c & 31) << 9) + lane * 8);
    }
    if (tid < 32) ((float4*)b1L)[tid] = ((const float4*)(b1 + ch * 128))[tid];
    if (tid == 0) uctr = 0;
    __syncthreads();

    for (;;) {
        int t = 0;
        if (lane == 0) t = atomicAdd(&uctr, 1);   // LDS atomic
        t = __shfl(t, 0);
        const int u = bslot + (t << 8);           // stride-256 across slots
        if (u >= NU) break;

        const int row = u * 16 + fl;              // this lane's atom
        const bool valid = row < N_ATOMS;
        const float* ap = A + (size_t)row * 256 + qd * 8;

        float4 c0, c1;
        if (valid) { c0 = *(const float4*)ap; c1 = *(const float4*)(ap + 4); }
        else       { c0 = make_float4(0, 0, 0, 0); c1 = c0; }

        float4_t acc[8] = {};
#pragma unroll
        for (int s = 0; s < 8; ++s) {
            float4 n0 = make_float4(0, 0, 0, 0), n1 = n0;
            if (s < 7 && valid) {                  // prefetch next k-step
                n0 = *(const float4*)(ap + (s + 1) * 32);
                n1 = *(const float4*)(ap + (s + 1) * 32 + 4);
            }
            union { uint32_t u4[4]; short8 s8; } cv;
            cv.u4[0] = pk(c0.x, c0.y); cv.u4[1] = pk(c0.z, c0.w);
            cv.u4[2] = pk(c1.x, c1.y); cv.u4[3] = pk(c1.z, c1.w);
            const int kc = s * 4 + qd;
#pragma unroll
            for (int j = 0; j < 8; ++j) {
                short8 wf = wfrag_h(Wlds, j * 16 + fl, kc);
                acc[j] = __builtin_amdgcn_mfma_f32_16x16x32_bf16(wf, cv.s8, acc[j], 0, 0, 0);
            }
            c0 = n0; c1 = n1;
        }

        if (valid) {
#pragma unroll
            for (int j = 0; j < 8; ++j) {
                int nl = j * 16 + qd * 4;          // local col
                float4 b4 = *(const float4*)&b1L[nl];
                uint2 o;
                o.x = pk(silu(acc[j][0] + b4.x), silu(acc[j][1] + b4.y));
                o.y = pk(silu(acc[j][2] + b4.z), silu(acc[j][3] + b4.w));
                *(uint2*)&H1[(size_t)row * 256 + ch * 128 + nl] = o;
            }
        }
    }
}

// ---------------------------------------------------------------------------
// Layer 2+3+pool: out[mol] += SCALE*(silu(H1@W2+b2).W3 + b3). Same col-split
// streaming structure (R10). Each col-half computes a PARTIAL W3-dot (the
// reduction is additive across col-halves); b3 added only by half 0.
// Pooling via per-block LDS bucket[1024], one global atomic per nonzero
// bucket at the end.
// ---------------------------------------------------------------------------
__global__ __launch_bounds__(512, 4)
void gemm2(const unsigned short* __restrict__ H1, const unsigned short* __restrict__ Wimg,
           const float* __restrict__ b2, const float* __restrict__ W3,
           const float* __restrict__ b3, const int* __restrict__ batch,
           float* __restrict__ out) {
    __shared__ unsigned short Wlds[32768];   // 64 KB
    __shared__ float bucket[NMOL];           // 4 KB
    __shared__ int uctr;

    const int tid = threadIdx.x;
    const int w = tid >> 6, lane = tid & 63;
    const int fl = lane & 15, qd = lane >> 4;
    const int ch = blockIdx.x >> 8;
    const int bslot = blockIdx.x & 255;

#pragma unroll
    for (int i = 0; i < 8; ++i) {
        int c = w * 8 + i;
        async16(&Wlds[c * 512],
                Wimg + ((c >> 5) << 15) + (ch << 14) + ((c & 31) << 9) + lane * 8);
    }
    bucket[tid] = 0.0f;
    bucket[tid + 512] = 0.0f;
    if (tid == 0) uctr = 0;
    __syncthreads();

    const float b3v = (ch == 0) ? b3[0] : 0.0f;   // add b3 once per atom
    float bbv[8], w3v[8];
#pragma unroll
    for (int nt = 0; nt < 8; ++nt) {
        bbv[nt] = b2[ch * 128 + nt * 16 + fl];
        w3v[nt] = W3[ch * 128 + nt * 16 + fl];
    }

    for (;;) {
        int t = 0;
        if (lane == 0) t = atomicAdd(&uctr, 1);
        t = __shfl(t, 0);
        const int u = bslot + (t << 8);
        if (u >= NU) break;

        const int ubase = u * 16;
        const int row = ubase + fl;
        const bool valid = row < N_ATOMS;
        const unsigned short* hp = H1 + (size_t)row * 256 + qd * 8;

        short8 h0 = (short8){0, 0, 0, 0, 0, 0, 0, 0};
        if (valid) h0 = *(const short8*)hp;

        float4_t acc[8] = {};
#pragma unroll
        for (int s = 0; s < 8; ++s) {
            short8 hn = (short8){0, 0, 0, 0, 0, 0, 0, 0};
            if (s < 7 && valid) hn = *(const short8*)(hp + (s + 1) * 32);
            const int kc = s * 4 + qd;
#pragma unroll
            for (int nt = 0; nt < 8; ++nt) {
                short8 wf = wfrag_h(Wlds, nt * 16 + fl, kc);
                acc[nt] = __builtin_amdgcn_mfma_f32_16x16x32_bf16(h0, wf, acc[nt], 0, 0, 0);
            }
            h0 = hn;
        }

        // acc[nt][r]: atom = ubase + qd*4 + r, col = ch*128 + nt*16 + fl
        float rs[4] = {};
#pragma unroll
        for (int nt = 0; nt < 8; ++nt)
#pragma unroll
            for (int r = 0; r < 4; ++r)
                rs[r] += silu(acc[nt][r] + bbv[nt]) * w3v[nt];
#pragma unroll
        for (int r = 0; r < 4; ++r) {
            float v = rs[r];
            v += __shfl_xor(v, 1);
            v += __shfl_xor(v, 2);
            v += __shfl_xor(v, 4);
            v += __shfl_xor(v, 8);
            rs[r] = v;
        }
        if (fl == 0) {
            int atom0 = ubase + qd * 4;
            if (atom0 < N_ATOMS) {   // atom0 % 4 == 0 -> all 4 rows valid
                int4 mb = *(const int4*)&batch[atom0];
                float v0 = rs[0] + b3v, v1 = rs[1] + b3v,
                      v2 = rs[2] + b3v, v3 = rs[3] + b3v;
                if (mb.x == mb.w) {
                    atomicAdd(&bucket[mb.x], (v0 + v1) + (v2 + v3));
                } else {
                    atomicAdd(&bucket[mb.x], v0);
                    atomicAdd(&bucket[mb.y], v1);
                    atomicAdd(&bucket[mb.z], v2);
                    atomicAdd(&bucket[mb.w], v3);
                }
            }
        }
    }
    __syncthreads();
#pragma unroll
    for (int i = 0; i < 2; ++i) {
        int m = tid + i * 512;
        float v = bucket[m];
        if (v != 0.0f) atomicAdd(&out[m], v * SCALE_C);
    }
}

// ---------------------------------------------------------------------------
extern "C" void kernel_launch(void* const* d_in, const int* in_sizes, int n_in,
                              void* d_out, int out_size, void* d_ws, size_t ws_size,
                              hipStream_t stream) {
    const float* A     = (const float*)d_in[0];
    const int*   batch = (const int*)d_in[1];
    const float* W1    = (const float*)d_in[2];
    const float* b1    = (const float*)d_in[3];
    const float* W2    = (const float*)d_in[4];
    const float* b2    = (const float*)d_in[5];
    const float* W3    = (const float*)d_in[6];
    const float* b3    = (const float*)d_in[7];
    float* out = (float*)d_out;

    unsigned short* H1  = (unsigned short*)d_ws;            // 100096*256 bf16
    unsigned short* W1i = H1 + (size_t)100096 * NFEAT;      // 65536 shorts
    unsigned short* W2i = W1i + 65536;                      // 65536 shorts

    prep<<<dim3(512), 256, 0, stream>>>(W1, W2, W1i, W2i, out);
    gemm1<<<dim3(512), 512, 0, stream>>>(A, W1i, b1, H1);
    gemm2<<<dim3(512), 512, 0, stream>>>(H1, W2i, b2, W3, b3, batch, out);
}